// Round 14
// baseline (225.027 us; speedup 1.0000x reference)
//
#include <hip/hip_runtime.h>

#define T_DIM 2048
#define B_DIM 32
#define F_DIM 1024
#define H_DIM 1024
#define PEN   -99999.0f

// d_out layout (floats)
#define SUM_OFF  0
#define DIST_OFF 32768
#define COPY_OFF 98304

// ws layout (floats)
#define WS_QPART 0              // [16][32][2048]  4 MB
#define WS_VPART 1048576        // [16][64][1024]  4 MB
#define WS_V     2097152        // [64][1024]
#define WS_CB    2162688        // [64]
#define WS_PML   2162752        // [32*64][4]
#define WS_PFACC 2170944        // [32*64][1024]   8 MB
#define WS_FBAR  4333632        // [32][1024]
#define WS_SPART 4366400        // [16][32][1024]  2 MB

#define NCHUNK   64             // t-chunks of 32 in fused pass
#define GFS      16             // f-split in gemm kernels
#define QJT      128            // j per gemm block

// part[fc][b][j] = sum_{f in chunk fc} X[b][f] * W[j][f]
// block tile: 128 j x 32 b x 64 f.  thread tile: 4j x 4b.
template<int J>
__global__ void gemm_part(const float* __restrict__ W, const float* __restrict__ X,
                          float* __restrict__ part) {
    __shared__ float swt[64 * QJT];   // [f][jj] swizzled, 32 KB
    __shared__ float sht[64 * 32];    // [f][b]  swizzled, 8 KB
    constexpr int NJ = J / QJT;
    int jt = blockIdx.x % NJ;
    int fc = blockIdx.x / NJ;
    int j0 = jt * QJT, f0 = fc * 64;
    int tid = threadIdx.x;
    for (int idx = tid; idx < 64 * QJT; idx += 256) {
        int jj = idx >> 6, f = idx & 63;
        swt[f * QJT + (jj ^ ((f & 7) << 2))] = W[(size_t)(j0 + jj) * F_DIM + f0 + f];
    }
    for (int idx = tid; idx < 64 * 32; idx += 256) {
        int b = idx >> 6, f = idx & 63;
        sht[f * 32 + (b ^ ((f & 7) << 2))] = X[b * F_DIM + f0 + f];
    }
    __syncthreads();
    int jg = tid & 31;          // j = j0 + jg*4 .. +3
    int bg = tid >> 5;          // b = bg*4 .. +3
    float acc[4][4];
    #pragma unroll
    for (int a = 0; a < 4; ++a)
        #pragma unroll
        for (int c = 0; c < 4; ++c) acc[a][c] = 0.f;
    #pragma unroll 8
    for (int f = 0; f < 64; ++f) {
        int sx = (f & 7) << 2;
        float4 wv = *(float4*)&swt[f * QJT + ((jg * 4) ^ sx)];
        float4 hv = *(float4*)&sht[f * 32 + ((bg * 4) ^ sx)];
        float w4[4] = {wv.x, wv.y, wv.z, wv.w};
        float h4[4] = {hv.x, hv.y, hv.z, hv.w};
        #pragma unroll
        for (int a = 0; a < 4; ++a)
            #pragma unroll
            for (int c = 0; c < 4; ++c)
                acc[a][c] += w4[a] * h4[c];
    }
    #pragma unroll
    for (int c = 0; c < 4; ++c) {
        float4 r = {acc[0][c], acc[1][c], acc[2][c], acc[3][c]};
        *(float4*)&part[((size_t)fc * 32 + bg * 4 + c) * J + j0 + jg * 4] = r;
    }
}

// blocks 0..255: vpart[hc][bc][f] = sum_{h in chunk} Wk[h][f] * q[b][2h+c]
//   with q[b][j] = bq[j] + sum_{fc<16} qpart[fc][b][j] summed inline at staging
// blocks 256..319: cb[bc] = dot(bk, q[b,:,c])  (64 balanced blocks)
__global__ void vproj_cb(const float* __restrict__ Wk, const float* __restrict__ bk,
                         const float* __restrict__ bq, const float* __restrict__ qpart,
                         float* __restrict__ vpart, float* __restrict__ cb) {
    int tid = threadIdx.x;
    if (blockIdx.x >= 256) {
        int bc = blockIdx.x - 256;
        int b = bc >> 1, c = bc & 1;
        float s = 0.f;
        for (int h = tid; h < H_DIM; h += 256) {
            int j = 2 * h + c;
            float q = bq[j];
            #pragma unroll
            for (int fc = 0; fc < GFS; ++fc)
                q += qpart[((size_t)fc * 32 + b) * 2048 + j];
            s += bk[h] * q;
        }
        __shared__ float red[256];
        red[tid] = s; __syncthreads();
        for (int st = 128; st; st >>= 1) {
            if (tid < st) red[tid] += red[tid + st];
            __syncthreads();
        }
        if (tid == 0) cb[bc] = red[0];
        return;
    }
    int ft = blockIdx.x & 15;       // f-tile of 64
    int hc = blockIdx.x >> 4;       // h-chunk of 64
    int f0 = ft * 64, h0 = hc * 64;
    __shared__ float sq2[64 * 64];  // [hh][bc], bc-dim XOR-swizzled (granule 4)
    for (int idx = tid; idx < 32 * 128; idx += 256) {
        int b = idx >> 7, jj = idx & 127;   // coalesced over jj
        int j = 2 * h0 + jj;
        float q = bq[j];
        #pragma unroll
        for (int fc = 0; fc < GFS; ++fc)
            q += qpart[((size_t)fc * 32 + b) * 2048 + j];
        int hh = jj >> 1, bc = 2 * b + (jj & 1);
        sq2[hh * 64 + (bc ^ ((hh & 7) << 2))] = q;
    }
    __syncthreads();
    int f = f0 + (tid & 63);
    int bcg = tid >> 6;             // 4 groups x 16 bc
    float acc[16];
    #pragma unroll
    for (int i = 0; i < 16; ++i) acc[i] = 0.f;
    #pragma unroll 4
    for (int hh = 0; hh < 64; ++hh) {
        float wk = Wk[(size_t)(h0 + hh) * F_DIM + f];
        int sx = (hh & 7) << 2;
        #pragma unroll
        for (int k = 0; k < 4; ++k) {
            float4 q4 = *(float4*)&sq2[hh * 64 + ((bcg * 16 + 4 * k) ^ sx)];
            acc[4 * k + 0] += wk * q4.x;
            acc[4 * k + 1] += wk * q4.y;
            acc[4 * k + 2] += wk * q4.z;
            acc[4 * k + 3] += wk * q4.w;
        }
    }
    #pragma unroll
    for (int i = 0; i < 16; ++i)
        vpart[((size_t)hc * 64 + bcg * 16 + i) * F_DIM + f] = acc[i];
}

__global__ void vreduce16(const float* __restrict__ vpart, float* __restrict__ v) {
    int i4 = blockIdx.x * 256 + threadIdx.x;   // float4 idx 0..16383
    float4 s = {0.f, 0.f, 0.f, 0.f};
    #pragma unroll
    for (int c = 0; c < 16; ++c) {
        float4 p = *(const float4*)(vpart + (size_t)c * 65536 + i4 * 4);
        s.x += p.x; s.y += p.y; s.z += p.z; s.w += p.w;
    }
    *(float4*)(v + i4 * 4) = s;
}

// Single pass over features: raw scores -> d_out; online (m,l); weighted feature sum.
// grid 2048 = 32 b x 64 chunks of 32 t; 8 rows per wave.
// Point-of-use loads (no prefetch) + min-6-waves/EU to test the occupancy lever.
__global__ __launch_bounds__(256, 6) void fused_pass(
        const float* __restrict__ feat, const float* __restrict__ v,
        const float* __restrict__ cb, const float* __restrict__ mask,
        float* __restrict__ out, float* __restrict__ pml, float* __restrict__ pfacc) {
    int b = blockIdx.x & 31;
    int chunk = blockIdx.x >> 5;       // 0..63
    int w = threadIdx.x >> 6;          // wave 0..3
    int lane = threadIdx.x & 63;

    float4 v0[4], v1[4];
    #pragma unroll
    for (int q = 0; q < 4; ++q) {
        v0[q] = *(const float4*)(v + (size_t)(b * 2 + 0) * F_DIM + q * 256 + lane * 4);
        v1[q] = *(const float4*)(v + (size_t)(b * 2 + 1) * F_DIM + q * 256 + lane * 4);
    }
    float c0 = cb[b * 2 + 0], c1 = cb[b * 2 + 1];

    float facc[16];
    #pragma unroll
    for (int i = 0; i < 16; ++i) facc[i] = 0.f;
    float m0 = -1e30f, l0 = 0.f, m1 = -1e30f, l1 = 0.f;

    int t0 = chunk * 32 + w * 8;

    for (int tt = 0; tt < 8; ++tt) {
        int t = t0 + tt;
        const float* frow = feat + ((size_t)t * B_DIM + b) * F_DIM;
        float4 fx[4];
        #pragma unroll
        for (int q = 0; q < 4; ++q) fx[q] = *(const float4*)(frow + q * 256 + lane * 4);
        float mpc = mask[t * B_DIM + b] * PEN;
        float a0 = 0.f, a1 = 0.f;
        #pragma unroll
        for (int q = 0; q < 4; ++q) {
            a0 += fx[q].x * v0[q].x + fx[q].y * v0[q].y + fx[q].z * v0[q].z + fx[q].w * v0[q].w;
            a1 += fx[q].x * v1[q].x + fx[q].y * v1[q].y + fx[q].z * v1[q].z + fx[q].w * v1[q].w;
        }
        for (int off = 32; off; off >>= 1) {
            a0 += __shfl_xor(a0, off, 64);
            a1 += __shfl_xor(a1, off, 64);
        }
        float s0 = a0 + c0 + mpc;
        float s1 = a1 + c1 + mpc;
        if (lane == 0) {
            out[DIST_OFF + t * B_DIM + b] = s0;
            out[COPY_OFF + t * B_DIM + b] = s1;
        }
        if (s0 > m0) {
            float sc = __expf(m0 - s0);
            l0 *= sc;
            #pragma unroll
            for (int i = 0; i < 16; ++i) facc[i] *= sc;
            m0 = s0;
        }
        float e0 = __expf(s0 - m0);
        l0 += e0;
        #pragma unroll
        for (int q = 0; q < 4; ++q) {
            facc[q * 4 + 0] += e0 * fx[q].x;
            facc[q * 4 + 1] += e0 * fx[q].y;
            facc[q * 4 + 2] += e0 * fx[q].z;
            facc[q * 4 + 3] += e0 * fx[q].w;
        }
        if (s1 > m1) { l1 *= __expf(m1 - s1); m1 = s1; }
        l1 += __expf(s1 - m1);
    }

    __shared__ float sfacc[4][F_DIM];   // 16 KB
    __shared__ float sml[4][4];
    #pragma unroll
    for (int q = 0; q < 4; ++q) {
        sfacc[w][q * 256 + lane * 4 + 0] = facc[q * 4 + 0];
        sfacc[w][q * 256 + lane * 4 + 1] = facc[q * 4 + 1];
        sfacc[w][q * 256 + lane * 4 + 2] = facc[q * 4 + 2];
        sfacc[w][q * 256 + lane * 4 + 3] = facc[q * 4 + 3];
    }
    if (lane == 0) {
        sml[w][0] = m0; sml[w][1] = l0; sml[w][2] = m1; sml[w][3] = l1;
    }
    __syncthreads();
    int tid = threadIdx.x;
    float M0 = fmaxf(fmaxf(sml[0][0], sml[1][0]), fmaxf(sml[2][0], sml[3][0]));
    float M1 = fmaxf(fmaxf(sml[0][2], sml[1][2]), fmaxf(sml[2][2], sml[3][2]));
    float L0 = 0.f, L1 = 0.f;
    float g[4];
    #pragma unroll
    for (int ww = 0; ww < 4; ++ww) {
        g[ww] = __expf(sml[ww][0] - M0);
        L0 += sml[ww][1] * g[ww];
        L1 += sml[ww][3] * __expf(sml[ww][2] - M1);
    }
    float4 r;
    r.x = g[0] * sfacc[0][tid * 4 + 0] + g[1] * sfacc[1][tid * 4 + 0]
        + g[2] * sfacc[2][tid * 4 + 0] + g[3] * sfacc[3][tid * 4 + 0];
    r.y = g[0] * sfacc[0][tid * 4 + 1] + g[1] * sfacc[1][tid * 4 + 1]
        + g[2] * sfacc[2][tid * 4 + 1] + g[3] * sfacc[3][tid * 4 + 1];
    r.z = g[0] * sfacc[0][tid * 4 + 2] + g[1] * sfacc[1][tid * 4 + 2]
        + g[2] * sfacc[2][tid * 4 + 2] + g[3] * sfacc[3][tid * 4 + 2];
    r.w = g[0] * sfacc[0][tid * 4 + 3] + g[1] * sfacc[1][tid * 4 + 3]
        + g[2] * sfacc[2][tid * 4 + 3] + g[3] * sfacc[3][tid * 4 + 3];
    *(float4*)(pfacc + ((size_t)(b * NCHUNK + chunk)) * F_DIM + tid * 4) = r;
    if (tid == 0) {
        float4 p = {M0, L0, M1, L1};
        *(float4*)(pml + (b * NCHUNK + chunk) * 4) = p;
    }
}

// blocks 0..63: normalize dist+copy in place (per-block redundant gml).
// blocks 64..127: fbar[b][f0:f0+512] = invL0 * sum_c exp(m_c - M0) * pfacc[b][c][f]
__global__ void epi(float* __restrict__ out, const float* __restrict__ pml,
                    const float* __restrict__ pfacc, float* __restrict__ fbar) {
    int tid = threadIdx.x;
    if (blockIdx.x < 64) {
        __shared__ float4 sml[32];
        if (tid < 32) {
            int b = tid;
            float M0 = -1e30f, L0 = 0.f, M1 = -1e30f, L1 = 0.f;
            for (int c = 0; c < NCHUNK; ++c) {
                float4 p = *(const float4*)(pml + (b * NCHUNK + c) * 4);
                float n0 = fmaxf(M0, p.x);
                L0 = L0 * __expf(M0 - n0) + p.y * __expf(p.x - n0);
                M0 = n0;
                float n1 = fmaxf(M1, p.z);
                L1 = L1 * __expf(M1 - n1) + p.w * __expf(p.z - n1);
                M1 = n1;
            }
            float4 g = {M0, 1.f / L0, M1, 1.f / L1};
            sml[b] = g;
        }
        __syncthreads();
        #pragma unroll
        for (int r = 0; r < 4; ++r) {
            int idx = blockIdx.x * 1024 + r * 256 + tid;
            float4 g = sml[idx & 31];
            out[DIST_OFF + idx] = __expf(out[DIST_OFF + idx] - g.x) * g.y;
            out[COPY_OFF + idx] = __expf(out[COPY_OFF + idx] - g.z) * g.w;
        }
        return;
    }
    int fb = blockIdx.x - 64;
    int b = fb >> 1;
    int f0 = (fb & 1) * 512;
    __shared__ float gm[2];
    if (tid < 64) {
        // 64 chunks == 64 lanes: butterfly online-merge of (m0, l0)
        float4 p = *(const float4*)(pml + (b * NCHUNK + tid) * 4);
        float m = p.x, l = p.y;
        for (int off = 32; off; off >>= 1) {
            float mo = __shfl_xor(m, off, 64);
            float lo = __shfl_xor(l, off, 64);
            float M = fmaxf(m, mo);
            l = l * __expf(m - M) + lo * __expf(mo - M);
            m = M;
        }
        if (tid == 0) { gm[0] = m; gm[1] = 1.f / l; }
    }
    __syncthreads();
    float M0 = gm[0], invL = gm[1];
    float s0 = 0.f, s1 = 0.f;
    for (int c = 0; c < NCHUNK; ++c) {
        float wc = __expf(pml[(b * NCHUNK + c) * 4] - M0);
        const float* pr = pfacc + ((size_t)(b * NCHUNK + c)) * F_DIM + f0 + tid;
        s0 += wc * pr[0];
        s1 += wc * pr[256];
    }
    fbar[b * F_DIM + f0 + tid] = s0 * invL;
    fbar[b * F_DIM + f0 + 256 + tid] = s1 * invL;
}

// out[b][j] = bm[j] + sum_{fc<16} spart[fc][b][j]
__global__ void sreduce16(const float* __restrict__ spart, const float* __restrict__ bm,
                          float* __restrict__ out) {
    int i4 = blockIdx.x * 256 + threadIdx.x;   // float4 idx 0..8191
    float4 s = *(const float4*)(bm + (i4 & 255) * 4);
    #pragma unroll
    for (int c = 0; c < 16; ++c) {
        float4 p = *(const float4*)(spart + (size_t)c * 32768 + i4 * 4);
        s.x += p.x; s.y += p.y; s.z += p.z; s.w += p.w;
    }
    *(float4*)(out + i4 * 4) = s;
}

extern "C" void kernel_launch(void* const* d_in, const int* in_sizes, int n_in,
                              void* d_out, int out_size, void* d_ws, size_t ws_size,
                              hipStream_t stream) {
    const float* feat   = (const float*)d_in[0];
    const float* hidden = (const float*)d_in[1];
    const float* mask   = (const float*)d_in[2];
    const float* Wk     = (const float*)d_in[3];
    const float* bk     = (const float*)d_in[4];
    const float* Wq     = (const float*)d_in[5];
    const float* bq     = (const float*)d_in[6];
    const float* Wm     = (const float*)d_in[7];
    const float* bm     = (const float*)d_in[8];
    float* out = (float*)d_out;
    float* ws  = (float*)d_ws;

    float* qpart = ws + WS_QPART;
    float* vpart = ws + WS_VPART;
    float* v     = ws + WS_V;
    float* cb    = ws + WS_CB;
    float* pml   = ws + WS_PML;
    float* pfacc = ws + WS_PFACC;
    float* fbar  = ws + WS_FBAR;
    float* spart = ws + WS_SPART;

    gemm_part<2048><<<(2048 / QJT) * GFS, 256, 0, stream>>>(Wq, hidden, qpart); // 256 blocks
    vproj_cb<<<320, 256, 0, stream>>>(Wk, bk, bq, qpart, vpart, cb);
    vreduce16<<<64, 256, 0, stream>>>(vpart, v);
    fused_pass<<<2048, 256, 0, stream>>>(feat, v, cb, mask, out, pml, pfacc);
    epi<<<128, 256, 0, stream>>>(out, pml, pfacc, fbar);
    gemm_part<1024><<<(1024 / QJT) * GFS, 256, 0, stream>>>(Wm, fbar, spart);   // 128 blocks
    sreduce16<<<32, 256, 0, stream>>>(spart, bm, out + SUM_OFF);
}

// Round 15
// 94.619 us; speedup vs baseline: 2.3783x; 2.3783x over previous
//
#include <hip/hip_runtime.h>

#define T_DIM 2048
#define B_DIM 32
#define F_DIM 1024
#define H_DIM 1024
#define PEN   -99999.0f

// d_out layout (floats)
#define SUM_OFF  0
#define DIST_OFF 32768
#define COPY_OFF 98304

// ws layout (floats)
#define WS_QPART 0              // [16][32][2048]  4 MB
#define WS_VPART 1048576        // [16][64][1024]  4 MB
#define WS_V     2097152        // [64][1024]
#define WS_CB    2162688        // [64]
#define WS_PML   2162752        // [32*64][4]
#define WS_PFACC 2170944        // [32*64][1024]   8 MB
#define WS_FBAR  4333632        // [32][1024]
#define WS_SPART 4366400        // [16][32][1024]  2 MB

#define NCHUNK   64             // t-chunks of 32 in fused pass
#define GFS      16             // f-split in gemm kernels
#define QJT      128            // j per gemm block

// part[fc][b][j] = sum_{f in chunk fc} X[b][f] * W[j][f]
// block tile: 128 j x 32 b x 64 f.  thread tile: 4j x 4b.
template<int J>
__global__ void gemm_part(const float* __restrict__ W, const float* __restrict__ X,
                          float* __restrict__ part) {
    __shared__ float swt[64 * QJT];   // [f][jj] swizzled, 32 KB
    __shared__ float sht[64 * 32];    // [f][b]  swizzled, 8 KB
    constexpr int NJ = J / QJT;
    int jt = blockIdx.x % NJ;
    int fc = blockIdx.x / NJ;
    int j0 = jt * QJT, f0 = fc * 64;
    int tid = threadIdx.x;
    for (int idx = tid; idx < 64 * QJT; idx += 256) {
        int jj = idx >> 6, f = idx & 63;
        swt[f * QJT + (jj ^ ((f & 7) << 2))] = W[(size_t)(j0 + jj) * F_DIM + f0 + f];
    }
    for (int idx = tid; idx < 64 * 32; idx += 256) {
        int b = idx >> 6, f = idx & 63;
        sht[f * 32 + (b ^ ((f & 7) << 2))] = X[b * F_DIM + f0 + f];
    }
    __syncthreads();
    int jg = tid & 31;          // j = j0 + jg*4 .. +3
    int bg = tid >> 5;          // b = bg*4 .. +3
    float acc[4][4];
    #pragma unroll
    for (int a = 0; a < 4; ++a)
        #pragma unroll
        for (int c = 0; c < 4; ++c) acc[a][c] = 0.f;
    #pragma unroll 8
    for (int f = 0; f < 64; ++f) {
        int sx = (f & 7) << 2;
        float4 wv = *(float4*)&swt[f * QJT + ((jg * 4) ^ sx)];
        float4 hv = *(float4*)&sht[f * 32 + ((bg * 4) ^ sx)];
        float w4[4] = {wv.x, wv.y, wv.z, wv.w};
        float h4[4] = {hv.x, hv.y, hv.z, hv.w};
        #pragma unroll
        for (int a = 0; a < 4; ++a)
            #pragma unroll
            for (int c = 0; c < 4; ++c)
                acc[a][c] += w4[a] * h4[c];
    }
    #pragma unroll
    for (int c = 0; c < 4; ++c) {
        float4 r = {acc[0][c], acc[1][c], acc[2][c], acc[3][c]};
        *(float4*)&part[((size_t)fc * 32 + bg * 4 + c) * J + j0 + jg * 4] = r;
    }
}

// blocks 0..255: vpart[hc][bc][f] = sum_{h in chunk} Wk[h][f] * q[b][2h+c]
//   with q[b][j] = bq[j] + sum_{fc<16} qpart[fc][b][j] summed inline at staging
// blocks 256..319: cb[bc] = dot(bk, q[b,:,c])  (64 balanced blocks)
__global__ void vproj_cb(const float* __restrict__ Wk, const float* __restrict__ bk,
                         const float* __restrict__ bq, const float* __restrict__ qpart,
                         float* __restrict__ vpart, float* __restrict__ cb) {
    int tid = threadIdx.x;
    if (blockIdx.x >= 256) {
        int bc = blockIdx.x - 256;
        int b = bc >> 1, c = bc & 1;
        float s = 0.f;
        for (int h = tid; h < H_DIM; h += 256) {
            int j = 2 * h + c;
            float q = bq[j];
            #pragma unroll
            for (int fc = 0; fc < GFS; ++fc)
                q += qpart[((size_t)fc * 32 + b) * 2048 + j];
            s += bk[h] * q;
        }
        __shared__ float red[256];
        red[tid] = s; __syncthreads();
        for (int st = 128; st; st >>= 1) {
            if (tid < st) red[tid] += red[tid + st];
            __syncthreads();
        }
        if (tid == 0) cb[bc] = red[0];
        return;
    }
    int ft = blockIdx.x & 15;       // f-tile of 64
    int hc = blockIdx.x >> 4;       // h-chunk of 64
    int f0 = ft * 64, h0 = hc * 64;
    __shared__ float sq2[64 * 64];  // [hh][bc], bc-dim XOR-swizzled (granule 4)
    for (int idx = tid; idx < 32 * 128; idx += 256) {
        int b = idx >> 7, jj = idx & 127;   // coalesced over jj
        int j = 2 * h0 + jj;
        float q = bq[j];
        #pragma unroll
        for (int fc = 0; fc < GFS; ++fc)
            q += qpart[((size_t)fc * 32 + b) * 2048 + j];
        int hh = jj >> 1, bc = 2 * b + (jj & 1);
        sq2[hh * 64 + (bc ^ ((hh & 7) << 2))] = q;
    }
    __syncthreads();
    int f = f0 + (tid & 63);
    int bcg = tid >> 6;             // 4 groups x 16 bc
    float acc[16];
    #pragma unroll
    for (int i = 0; i < 16; ++i) acc[i] = 0.f;
    #pragma unroll 4
    for (int hh = 0; hh < 64; ++hh) {
        float wk = Wk[(size_t)(h0 + hh) * F_DIM + f];
        int sx = (hh & 7) << 2;
        #pragma unroll
        for (int k = 0; k < 4; ++k) {
            float4 q4 = *(float4*)&sq2[hh * 64 + ((bcg * 16 + 4 * k) ^ sx)];
            acc[4 * k + 0] += wk * q4.x;
            acc[4 * k + 1] += wk * q4.y;
            acc[4 * k + 2] += wk * q4.z;
            acc[4 * k + 3] += wk * q4.w;
        }
    }
    #pragma unroll
    for (int i = 0; i < 16; ++i)
        vpart[((size_t)hc * 64 + bcg * 16 + i) * F_DIM + f] = acc[i];
}

__global__ void vreduce16(const float* __restrict__ vpart, float* __restrict__ v) {
    int i4 = blockIdx.x * 256 + threadIdx.x;   // float4 idx 0..16383
    float4 s = {0.f, 0.f, 0.f, 0.f};
    #pragma unroll
    for (int c = 0; c < 16; ++c) {
        float4 p = *(const float4*)(vpart + (size_t)c * 65536 + i4 * 4);
        s.x += p.x; s.y += p.y; s.z += p.z; s.w += p.w;
    }
    *(float4*)(v + i4 * 4) = s;
}

// Single pass over features: raw scores -> d_out; online (m,l); weighted feature sum.
// grid 2048 = 32 b x 64 chunks of 32 t; 8 rows per wave.
__global__ __launch_bounds__(256) void fused_pass(
        const float* __restrict__ feat, const float* __restrict__ v,
        const float* __restrict__ cb, const float* __restrict__ mask,
        float* __restrict__ out, float* __restrict__ pml, float* __restrict__ pfacc) {
    int b = blockIdx.x & 31;
    int chunk = blockIdx.x >> 5;       // 0..63
    int w = threadIdx.x >> 6;          // wave 0..3
    int lane = threadIdx.x & 63;

    float4 v0[4], v1[4];
    #pragma unroll
    for (int q = 0; q < 4; ++q) {
        v0[q] = *(const float4*)(v + (size_t)(b * 2 + 0) * F_DIM + q * 256 + lane * 4);
        v1[q] = *(const float4*)(v + (size_t)(b * 2 + 1) * F_DIM + q * 256 + lane * 4);
    }
    float c0 = cb[b * 2 + 0], c1 = cb[b * 2 + 1];

    float facc[16];
    #pragma unroll
    for (int i = 0; i < 16; ++i) facc[i] = 0.f;
    float m0 = -1e30f, l0 = 0.f, m1 = -1e30f, l1 = 0.f;

    int t0 = chunk * 32 + w * 8;
    const float* frow = feat + ((size_t)t0 * B_DIM + b) * F_DIM;
    float4 fcur[4];
    #pragma unroll
    for (int q = 0; q < 4; ++q) fcur[q] = *(const float4*)(frow + q * 256 + lane * 4);
    float mpc = mask[t0 * B_DIM + b] * PEN;

    for (int tt = 0; tt < 8; ++tt) {
        int t = t0 + tt;
        float4 fx[4];
        #pragma unroll
        for (int q = 0; q < 4; ++q) fx[q] = fcur[q];
        float mpn = mpc;
        if (tt < 7) {
            const float* fn = feat + ((size_t)(t + 1) * B_DIM + b) * F_DIM;
            #pragma unroll
            for (int q = 0; q < 4; ++q) fcur[q] = *(const float4*)(fn + q * 256 + lane * 4);
            mpn = mask[(t + 1) * B_DIM + b] * PEN;
        }
        float a0 = 0.f, a1 = 0.f;
        #pragma unroll
        for (int q = 0; q < 4; ++q) {
            a0 += fx[q].x * v0[q].x + fx[q].y * v0[q].y + fx[q].z * v0[q].z + fx[q].w * v0[q].w;
            a1 += fx[q].x * v1[q].x + fx[q].y * v1[q].y + fx[q].z * v1[q].z + fx[q].w * v1[q].w;
        }
        for (int off = 32; off; off >>= 1) {
            a0 += __shfl_xor(a0, off, 64);
            a1 += __shfl_xor(a1, off, 64);
        }
        float s0 = a0 + c0 + mpc;
        float s1 = a1 + c1 + mpc;
        if (lane == 0) {
            out[DIST_OFF + t * B_DIM + b] = s0;
            out[COPY_OFF + t * B_DIM + b] = s1;
        }
        if (s0 > m0) {
            float sc = __expf(m0 - s0);
            l0 *= sc;
            #pragma unroll
            for (int i = 0; i < 16; ++i) facc[i] *= sc;
            m0 = s0;
        }
        float e0 = __expf(s0 - m0);
        l0 += e0;
        #pragma unroll
        for (int q = 0; q < 4; ++q) {
            facc[q * 4 + 0] += e0 * fx[q].x;
            facc[q * 4 + 1] += e0 * fx[q].y;
            facc[q * 4 + 2] += e0 * fx[q].z;
            facc[q * 4 + 3] += e0 * fx[q].w;
        }
        if (s1 > m1) { l1 *= __expf(m1 - s1); m1 = s1; }
        l1 += __expf(s1 - m1);
        mpc = mpn;
    }

    __shared__ float sfacc[4][F_DIM];   // 16 KB
    __shared__ float sml[4][4];
    #pragma unroll
    for (int q = 0; q < 4; ++q) {
        sfacc[w][q * 256 + lane * 4 + 0] = facc[q * 4 + 0];
        sfacc[w][q * 256 + lane * 4 + 1] = facc[q * 4 + 1];
        sfacc[w][q * 256 + lane * 4 + 2] = facc[q * 4 + 2];
        sfacc[w][q * 256 + lane * 4 + 3] = facc[q * 4 + 3];
    }
    if (lane == 0) {
        sml[w][0] = m0; sml[w][1] = l0; sml[w][2] = m1; sml[w][3] = l1;
    }
    __syncthreads();
    int tid = threadIdx.x;
    float M0 = fmaxf(fmaxf(sml[0][0], sml[1][0]), fmaxf(sml[2][0], sml[3][0]));
    float M1 = fmaxf(fmaxf(sml[0][2], sml[1][2]), fmaxf(sml[2][2], sml[3][2]));
    float L0 = 0.f, L1 = 0.f;
    float g[4];
    #pragma unroll
    for (int ww = 0; ww < 4; ++ww) {
        g[ww] = __expf(sml[ww][0] - M0);
        L0 += sml[ww][1] * g[ww];
        L1 += sml[ww][3] * __expf(sml[ww][2] - M1);
    }
    float4 r;
    r.x = g[0] * sfacc[0][tid * 4 + 0] + g[1] * sfacc[1][tid * 4 + 0]
        + g[2] * sfacc[2][tid * 4 + 0] + g[3] * sfacc[3][tid * 4 + 0];
    r.y = g[0] * sfacc[0][tid * 4 + 1] + g[1] * sfacc[1][tid * 4 + 1]
        + g[2] * sfacc[2][tid * 4 + 1] + g[3] * sfacc[3][tid * 4 + 1];
    r.z = g[0] * sfacc[0][tid * 4 + 2] + g[1] * sfacc[1][tid * 4 + 2]
        + g[2] * sfacc[2][tid * 4 + 2] + g[3] * sfacc[3][tid * 4 + 2];
    r.w = g[0] * sfacc[0][tid * 4 + 3] + g[1] * sfacc[1][tid * 4 + 3]
        + g[2] * sfacc[2][tid * 4 + 3] + g[3] * sfacc[3][tid * 4 + 3];
    *(float4*)(pfacc + ((size_t)(b * NCHUNK + chunk)) * F_DIM + tid * 4) = r;
    if (tid == 0) {
        float4 p = {M0, L0, M1, L1};
        *(float4*)(pml + (b * NCHUNK + chunk) * 4) = p;
    }
}

// blocks 0..63: normalize dist+copy in place (per-block redundant gml).
// blocks 64..127: fbar[b][f0:f0+512] = invL0 * sum_c exp(m_c - M0) * pfacc[b][c][f]
__global__ void epi(float* __restrict__ out, const float* __restrict__ pml,
                    const float* __restrict__ pfacc, float* __restrict__ fbar) {
    int tid = threadIdx.x;
    if (blockIdx.x < 64) {
        __shared__ float4 sml[32];
        if (tid < 32) {
            int b = tid;
            float M0 = -1e30f, L0 = 0.f, M1 = -1e30f, L1 = 0.f;
            for (int c = 0; c < NCHUNK; ++c) {
                float4 p = *(const float4*)(pml + (b * NCHUNK + c) * 4);
                float n0 = fmaxf(M0, p.x);
                L0 = L0 * __expf(M0 - n0) + p.y * __expf(p.x - n0);
                M0 = n0;
                float n1 = fmaxf(M1, p.z);
                L1 = L1 * __expf(M1 - n1) + p.w * __expf(p.z - n1);
                M1 = n1;
            }
            float4 g = {M0, 1.f / L0, M1, 1.f / L1};
            sml[b] = g;
        }
        __syncthreads();
        #pragma unroll
        for (int r = 0; r < 4; ++r) {
            int idx = blockIdx.x * 1024 + r * 256 + tid;
            float4 g = sml[idx & 31];
            out[DIST_OFF + idx] = __expf(out[DIST_OFF + idx] - g.x) * g.y;
            out[COPY_OFF + idx] = __expf(out[COPY_OFF + idx] - g.z) * g.w;
        }
        return;
    }
    int fb = blockIdx.x - 64;
    int b = fb >> 1;
    int f0 = (fb & 1) * 512;
    __shared__ float gm[2];
    if (tid < 64) {
        // 64 chunks == 64 lanes: butterfly online-merge of (m0, l0)
        float4 p = *(const float4*)(pml + (b * NCHUNK + tid) * 4);
        float m = p.x, l = p.y;
        for (int off = 32; off; off >>= 1) {
            float mo = __shfl_xor(m, off, 64);
            float lo = __shfl_xor(l, off, 64);
            float M = fmaxf(m, mo);
            l = l * __expf(m - M) + lo * __expf(mo - M);
            m = M;
        }
        if (tid == 0) { gm[0] = m; gm[1] = 1.f / l; }
    }
    __syncthreads();
    float M0 = gm[0], invL = gm[1];
    float s0 = 0.f, s1 = 0.f;
    for (int c = 0; c < NCHUNK; ++c) {
        float wc = __expf(pml[(b * NCHUNK + c) * 4] - M0);
        const float* pr = pfacc + ((size_t)(b * NCHUNK + c)) * F_DIM + f0 + tid;
        s0 += wc * pr[0];
        s1 += wc * pr[256];
    }
    fbar[b * F_DIM + f0 + tid] = s0 * invL;
    fbar[b * F_DIM + f0 + 256 + tid] = s1 * invL;
}

// out[b][j] = bm[j] + sum_{fc<16} spart[fc][b][j]
__global__ void sreduce16(const float* __restrict__ spart, const float* __restrict__ bm,
                          float* __restrict__ out) {
    int i4 = blockIdx.x * 256 + threadIdx.x;   // float4 idx 0..8191
    float4 s = *(const float4*)(bm + (i4 & 255) * 4);
    #pragma unroll
    for (int c = 0; c < 16; ++c) {
        float4 p = *(const float4*)(spart + (size_t)c * 32768 + i4 * 4);
        s.x += p.x; s.y += p.y; s.z += p.z; s.w += p.w;
    }
    *(float4*)(out + i4 * 4) = s;
}

extern "C" void kernel_launch(void* const* d_in, const int* in_sizes, int n_in,
                              void* d_out, int out_size, void* d_ws, size_t ws_size,
                              hipStream_t stream) {
    const float* feat   = (const float*)d_in[0];
    const float* hidden = (const float*)d_in[1];
    const float* mask   = (const float*)d_in[2];
    const float* Wk     = (const float*)d_in[3];
    const float* bk     = (const float*)d_in[4];
    const float* Wq     = (const float*)d_in[5];
    const float* bq     = (const float*)d_in[6];
    const float* Wm     = (const float*)d_in[7];
    const float* bm     = (const float*)d_in[8];
    float* out = (float*)d_out;
    float* ws  = (float*)d_ws;

    float* qpart = ws + WS_QPART;
    float* vpart = ws + WS_VPART;
    float* v     = ws + WS_V;
    float* cb    = ws + WS_CB;
    float* pml   = ws + WS_PML;
    float* pfacc = ws + WS_PFACC;
    float* fbar  = ws + WS_FBAR;
    float* spart = ws + WS_SPART;

    gemm_part<2048><<<(2048 / QJT) * GFS, 256, 0, stream>>>(Wq, hidden, qpart); // 256 blocks
    vproj_cb<<<320, 256, 0, stream>>>(Wk, bk, bq, qpart, vpart, cb);
    vreduce16<<<64, 256, 0, stream>>>(vpart, v);
    fused_pass<<<2048, 256, 0, stream>>>(feat, v, cb, mask, out, pml, pfacc);
    epi<<<128, 256, 0, stream>>>(out, pml, pfacc, fbar);
    gemm_part<1024><<<(1024 / QJT) * GFS, 256, 0, stream>>>(Wm, fbar, spart);   // 128 blocks
    sreduce16<<<32, 256, 0, stream>>>(spart, bm, out + SUM_OFF);
}